// Round 7
// baseline (326.346 us; speedup 1.0000x reference)
//
#include <hip/hip_runtime.h>
#include <hip/hip_fp16.h>

#define TT 512
#define BB 1024
#define VV 96
#define LL 48

__device__ __forceinline__ int f2i(float x) { return __float_as_int(x); }
__device__ __forceinline__ float i2f(int x) { return __int_as_float(x); }

template <int CTRL, int RM, int BM, bool BC>
__device__ __forceinline__ float dppf(float old, float src) {
    return i2f(__builtin_amdgcn_update_dpp(f2i(old), f2i(src), CTRL, RM, BM, BC));
}

// Full-wave sum via DPP butterfly (verified); broadcast via lane 63.
__device__ __forceinline__ float wave_sum(float v) {
    v += dppf<0xB1, 0xF, 0xF, true>(0.f, v);   // quad_perm [1,0,3,2]
    v += dppf<0x4E, 0xF, 0xF, true>(0.f, v);   // quad_perm [2,3,0,1]
    v += dppf<0x141, 0xF, 0xF, true>(0.f, v);  // row_half_mirror
    v += dppf<0x140, 0xF, 0xF, true>(0.f, v);  // row_mirror
    v += dppf<0x142, 0xA, 0xF, false>(0.f, v); // row_bcast15
    v += dppf<0x143, 0xC, 0xF, false>(0.f, v); // row_bcast31
    return i2f(__builtin_amdgcn_readlane(f2i(v), 63));
}

// Full-wave max (nonnegative inputs; old=0 is neutral).
__device__ __forceinline__ float wave_max(float v) {
    v = fmaxf(v, dppf<0xB1, 0xF, 0xF, true>(0.f, v));
    v = fmaxf(v, dppf<0x4E, 0xF, 0xF, true>(0.f, v));
    v = fmaxf(v, dppf<0x141, 0xF, 0xF, true>(0.f, v));
    v = fmaxf(v, dppf<0x140, 0xF, 0xF, true>(0.f, v));
    v = fmaxf(v, dppf<0x142, 0xA, 0xF, false>(0.f, v));
    v = fmaxf(v, dppf<0x143, 0xC, 0xF, false>(0.f, v));
    return i2f(__builtin_amdgcn_readlane(f2i(v), 63));
}

// Phase-split version of the verified round-6 kernel (same packed-pair state
// layout, same meet-in-the-middle halves, same renorm + f64-dot epilogue):
//   Phase 1 (parallel, BW-bound): each wave stages E for its 256 rows into
//     LDS (El[t][l] f16, Eb[t] f32) — exp/wave_sum/rcp run pipelined across
//     independent rows, off the serial critical path.
//   Phase 2 (serial, LDS-only): 256 recurrence steps, per step = 2 LDS reads
//     (4-deep register E pipeline) + 1-2 DPP + ~6 VALU. No loads, no exp.
// No barrier between phases: each wave reads only its own staged half.
__global__ __launch_bounds__(128) void ctc_split_lds(
        const int* __restrict__ labels,
        const float* __restrict__ yp,
        float* __restrict__ loss) {
    const int b = blockIdx.x;
    const int tid = threadIdx.x;
    const int wid = tid >> 6;
    const int l = tid & 63;
    const int* lb = labels + b * LL;

    const int ll = (l < 48) ? l : 47;        // clamped label index / f2 slot
    const int lbl = lb[ll];
    const bool lab = (l < 48);               // lane owns a real odd state
    const bool skF = (l >= 1) && lab && (lb[l - 1] != lbl);
    const bool skB = (l < 47) && (lb[l + 1] != lbl);

    const float* base = yp + (size_t)b * VV;
    const size_t rstep = (size_t)BB * VV;

    __shared__ __half sEl[2][256][48];   // 48 KiB
    __shared__ float  sEb[2][256];       // 2 KiB
    __shared__ float  sBe[64];
    __shared__ float  sBo[64];
    __shared__ int    sS2b;

    // ---------------- phase 1: stage E into LDS (parallel over rows) -------
    // wid0: slot j <- row j (t = 0..255); wid1: slot j <- row 511-j.
    {
        float2 ringD[8];
        float  ringL[8];
        #pragma unroll
        for (int j = 0; j < 8; ++j) {
            const int row = wid ? (511 - j) : j;
            const float* rp = base + (size_t)row * rstep;
            ringD[j] = *(const float2*)(rp + 2 * ll);
            ringL[j] = rp[lbl];
        }
        for (int o = 0; o < 32; ++o) {
            #pragma unroll
            for (int tt = 0; tt < 8; ++tt) {
                const int j = 8 * o + tt;
                float ex0 = __expf(ringD[tt].x), ex1 = __expf(ringD[tt].y);
                float exl = __expf(ringL[tt]);
                float se = lab ? (ex0 + ex1) : 0.f;
                float tot = wave_sum(se);
                float r96 = 96.0f * __builtin_amdgcn_rcpf(tot);
                if (lab) sEl[wid][j][l] = __float2half(exl * r96);
                if (l == 0) sEb[wid][j] = ex0 * r96;
                int jn = j + 8; if (jn > 255) jn = 255;   // dup loads, unused
                const int row = wid ? (511 - jn) : jn;
                const float* rp = base + (size_t)row * rstep;
                ringD[tt] = *(const float2*)(rp + 2 * ll);
                ringL[tt] = rp[lbl];
            }
        }
    }

    // ---------------- phase 2: serial scan (LDS-only) ----------------------
    float Ae, Ao;
    int S2 = 0;
    float EB0, EL0, EB1, EL1, EB2, EL2, EB3, EL3;   // 4-deep E pipeline

#define LOADE(K, EB, EL) { \
        EB = sEb[wid][K]; \
        EL = lab ? __half2float(sEl[wid][K][ll]) : 0.f; }

#define RENORM { \
        float vm = fmaxf(Ae, Ao); \
        float m = wave_max(vm); \
        int eb_ = (f2i(m) >> 23) & 0xFF; \
        float sc = i2f((254 - eb_) << 23); \
        Ae *= sc; Ao *= sc; \
        S2 += eb_ - 127; }

    // forward step (packed-pair update, verified round 6)
#define FSTEP(K, EB, EL) { \
        float sh = dppf<0x138, 0xF, 0xF, false>(0.f, Ao); \
        float AeN = (Ae + sh) * EB; \
        float AoN = (Ao + Ae + (skF ? sh : 0.f)) * EL; \
        Ae = AeN; Ao = AoN; \
        int kn = (K) + 4; if (kn > 255) kn = 255; \
        LOADE(kn, EB, EL) }

    // backward (adjoint) step (verified round 6)
#define BSTEP(K, EB, EL) { \
        float wE = Ae * EB; \
        float wO = Ao * EL; \
        float sE = dppf<0x130, 0xF, 0xF, false>(0.f, wE); \
        float sO = dppf<0x130, 0xF, 0xF, false>(0.f, wO); \
        Ae = wE + wO; \
        Ao = wO + sE + (skB ? sO : 0.f); \
        int kn = (K) + 4; if (kn > 255) kn = 255; \
        LOADE(kn, EB, EL) }

    LOADE(0, EB0, EL0)
    LOADE(1, EB1, EL1)
    LOADE(2, EB2, EL2)
    LOADE(3, EB3, EL3)

    if (wid == 0) {
        // forward: rows 0..255 (slot k = row k)
        Ae = (l == 0) ? 1.f : 0.f;   // delta at state 0; step 0 rebuilds alpha0
        Ao = 0.f;
        for (int o = 0; o < 8; ++o) {
            for (int u = 0; u < 4; ++u) {
                const int k0 = 32 * o + 8 * u;
                FSTEP(k0 + 0, EB0, EL0)
                FSTEP(k0 + 1, EB1, EL1)
                FSTEP(k0 + 2, EB2, EL2)
                FSTEP(k0 + 3, EB3, EL3)
                FSTEP(k0 + 4, EB0, EL0)
                FSTEP(k0 + 5, EB1, EL1)
                FSTEP(k0 + 6, EB2, EL2)
                FSTEP(k0 + 7, EB3, EL3)
            }
            RENORM
        }
    } else {
        // backward adjoint: applies rows 511..256 (slot k = row 511-k)
        Ae = (l == 48) ? 1.f : 0.f;   // state 96
        Ao = (l == 47) ? 1.f : 0.f;   // state 95
        for (int o = 0; o < 8; ++o) {
            for (int u = 0; u < 4; ++u) {
                const int k0 = 32 * o + 8 * u;
                BSTEP(k0 + 0, EB0, EL0)
                BSTEP(k0 + 1, EB1, EL1)
                BSTEP(k0 + 2, EB2, EL2)
                BSTEP(k0 + 3, EB3, EL3)
                BSTEP(k0 + 4, EB0, EL0)
                BSTEP(k0 + 5, EB1, EL1)
                BSTEP(k0 + 6, EB2, EL2)
                BSTEP(k0 + 7, EB3, EL3)
            }
            RENORM
        }
        sBe[l] = Ae;
        sBo[l] = Ao;
        if (l == 0) sS2b = S2;
    }
    __syncthreads();
    if (wid == 0) {
        // f64 dot (components can f32-underflow: ~2^-130; f64 min 2^-1022)
        double pd = (double)Ae * (double)sBe[l] + (double)Ao * (double)sBo[l];
        #pragma unroll
        for (int m = 1; m < 64; m <<= 1) pd += __shfl_xor(pd, m);
        if (l == 0) {
            long long ud = __double_as_longlong(pd);
            int eb = (int)((ud >> 52) & 0x7FF);             // biased exponent
            double md = __longlong_as_double(
                (ud & 0x000FFFFFFFFFFFFFLL) | 0x3FF0000000000000LL); // [1,2)
            int s2tot = S2 + sS2b + (eb - 1023);
            loss[b] = 2336.946274031532f
                    - (float)s2tot * 0.6931471805599453f
                    - __logf((float)md);
        }
    }
#undef LOADE
#undef RENORM
#undef FSTEP
#undef BSTEP
}

__global__ __launch_bounds__(256) void ctc_mean_kernel(
        const float* __restrict__ loss, float* __restrict__ out) {
    const int tid = threadIdx.x;
    float v = loss[tid] + loss[tid + 256] + loss[tid + 512] + loss[tid + 768];
    #pragma unroll
    for (int m = 1; m < 64; m <<= 1) v += __shfl_xor(v, m);
    __shared__ float part[4];
    if ((tid & 63) == 0) part[tid >> 6] = v;
    __syncthreads();
    if (tid == 0) out[0] = (part[0] + part[1] + part[2] + part[3]) * (1.0f / (float)BB);
}

extern "C" void kernel_launch(void* const* d_in, const int* in_sizes, int n_in,
                              void* d_out, int out_size, void* d_ws, size_t ws_size,
                              hipStream_t stream) {
    const int* y_true = (const int*)d_in[0];     // [B, L] int32
    const float* y_pred = (const float*)d_in[1]; // [T, B, V] float32
    float* out = (float*)d_out;
    float* lossbuf = (float*)d_ws;               // [B] floats

    ctc_split_lds<<<BB, 128, 0, stream>>>(y_true, y_pred, lossbuf);
    ctc_mean_kernel<<<1, 256, 0, stream>>>(lossbuf, out);
}

// Round 9
// 276.449 us; speedup vs baseline: 1.1805x; 1.1805x over previous
//
#include <hip/hip_runtime.h>

#define TT 512
#define BB 1024
#define VV 96
#define LL 48
#define NCH 32          // chunks per half; 8 rows (timesteps) per chunk

__device__ __forceinline__ int f2i(float x) { return __float_as_int(x); }
__device__ __forceinline__ float i2f(int x) { return __int_as_float(x); }

template <int CTRL, int RM, int BM, bool BC>
__device__ __forceinline__ float dppf(float old, float src) {
    return i2f(__builtin_amdgcn_update_dpp(f2i(old), f2i(src), CTRL, RM, BM, BC));
}

// Full-wave sum via DPP butterfly (verified); broadcast via lane 63.
__device__ __forceinline__ float wave_sum(float v) {
    v += dppf<0xB1, 0xF, 0xF, true>(0.f, v);   // quad_perm [1,0,3,2]
    v += dppf<0x4E, 0xF, 0xF, true>(0.f, v);   // quad_perm [2,3,0,1]
    v += dppf<0x141, 0xF, 0xF, true>(0.f, v);  // row_half_mirror
    v += dppf<0x140, 0xF, 0xF, true>(0.f, v);  // row_mirror
    v += dppf<0x142, 0xA, 0xF, false>(0.f, v); // row_bcast15
    v += dppf<0x143, 0xC, 0xF, false>(0.f, v); // row_bcast31
    return i2f(__builtin_amdgcn_readlane(f2i(v), 63));
}

// Full-wave max (nonnegative inputs; old=0 is neutral).
__device__ __forceinline__ float wave_max(float v) {
    v = fmaxf(v, dppf<0xB1, 0xF, 0xF, true>(0.f, v));
    v = fmaxf(v, dppf<0x4E, 0xF, 0xF, true>(0.f, v));
    v = fmaxf(v, dppf<0x141, 0xF, 0xF, true>(0.f, v));
    v = fmaxf(v, dppf<0x140, 0xF, 0xF, true>(0.f, v));
    v = fmaxf(v, dppf<0x142, 0xA, 0xF, false>(0.f, v));
    v = fmaxf(v, dppf<0x143, 0xC, 0xF, false>(0.f, v));
    return i2f(__builtin_amdgcn_readlane(f2i(v), 63));
}

// Block-cooperative coalesced CTC halves.
// Grid 256 = 128 b-groups x 2 directions. Block: 512 thr = 8 waves; wave w
// owns batch element b = bgrp*8+w and runs the verified packed-pair serial
// recurrence (R6) for ONE direction of the verified meet-in-the-middle split
// (R5): dir0 = forward rows 0..255, dir1 = backward-adjoint rows 511..256.
// Memory: per 8-row chunk, the block's 8 waves each load their row's 3 KiB
// slice [t, b0:b0+8, :] as 3 contiguous 1-KiB float4 wave-loads (fixes the
// 384B@384KiB-stride pattern that capped R0-R7 at ~0.8-2 TB/s, measured
// directly in R7: 770 GB/s), staged through one 24-KiB LDS buffer with
// issue-early/write-late pipelining. Results (Ae/Ao + S2) -> workspace;
// combine kernel does the verified f64 dot + exponent-peel epilogue.
__global__ __launch_bounds__(512) void ctc_halves(
        const int* __restrict__ labels,
        const float* __restrict__ yp,
        float* __restrict__ ws) {
    const int bgrp = blockIdx.x & 127;
    const int dir  = blockIdx.x >> 7;
    const int tid = threadIdx.x;
    const int w = tid >> 6;
    const int l = tid & 63;
    const int b = bgrp * 8 + w;
    const int* lb = labels + b * LL;

    const int ll  = (l < 48) ? l : 47;       // clamped label index
    const int lbl = lb[ll];
    const bool lab = (l < 48);               // lane owns odd state 2l+1
    const bool skF = (l >= 1) && lab && (lb[l - 1] != lbl);
    const bool skB = (l < 47) && (lb[l + 1] != lbl);

    const size_t rstep = (size_t)BB * VV;
    const float* gbase = yp + (size_t)bgrp * (8 * VV);

    __shared__ float sE[8 * 768];            // 24 KiB: [row slot][8 b x 96]

    // global row pointer for chunk c, this wave's row slot (= w)
    auto rowp = [&](int c) -> const float4* {
        const int k = 8 * c + w;
        const int t = dir ? (511 - k) : k;
        return (const float4*)(gbase + (size_t)t * rstep);
    };

    float4 p0, p1, p2, q0, q1, q2;

    // prologue: chunk 0 -> LDS; chunk 1 -> regs
    { const float4* rp = rowp(0); p0 = rp[l]; p1 = rp[64 + l]; p2 = rp[128 + l]; }
    { float4* dst = (float4*)&sE[w * 768]; dst[l] = p0; dst[64 + l] = p1; dst[128 + l] = p2; }
    { const float4* rp = rowp(1); p0 = rp[l]; p1 = rp[64 + l]; p2 = rp[128 + l]; }
    q0 = p0; q1 = p1; q2 = p2;               // defined even when not reloaded
    __syncthreads();

    float Ae, Ao;
    int S2 = 0;
    if (dir == 0) { Ae = (l == 0) ? 1.f : 0.f; Ao = 0.f; }                   // delta at state 0
    else          { Ae = (l == 48) ? 1.f : 0.f; Ao = (l == 47) ? 1.f : 0.f; } // u = e96 + e95

    for (int c = 0; c < NCH; ++c) {
        // ---- emissions for the chunk's 8 rows (independent -> pipelined) ----
        float Ebv[8], Elv[8];                // statically indexed after unroll
        #pragma unroll
        for (int r = 0; r < 8; ++r) {
            const float* rb = &sE[r * 768 + w * 96];
            float2 d = *(const float2*)(rb + 2 * ll);
            float elg = rb[lbl];
            float ex0 = __expf(d.x), ex1 = __expf(d.y), exl = __expf(elg);
            float se = lab ? (ex0 + ex1) : 0.f;
            float tot = wave_sum(se);
            float r96 = 96.0f * __builtin_amdgcn_rcpf(tot);
            Ebv[r] = i2f(__builtin_amdgcn_readfirstlane(f2i(ex0))) * r96;
            Elv[r] = lab ? exl * r96 : 0.f;
        }
        // ---- issue chunk c+2 loads early (hidden under serial steps) ----
        if (c + 2 < NCH) {
            const float4* rp = rowp(c + 2);
            q0 = rp[l]; q1 = rp[64 + l]; q2 = rp[128 + l];
        }
        // ---- 8 serial recurrence steps (R6-verified packed-pair update) ----
        if (dir == 0) {
            #pragma unroll
            for (int r = 0; r < 8; ++r) {
                float sh = dppf<0x138, 0xF, 0xF, false>(0.f, Ao);   // shr1
                float AeN = (Ae + sh) * Ebv[r];
                float AoN = (Ao + Ae + (skF ? sh : 0.f)) * Elv[r];
                Ae = AeN; Ao = AoN;
            }
        } else {
            #pragma unroll
            for (int r = 0; r < 8; ++r) {
                float wE = Ae * Ebv[r];
                float wO = Ao * Elv[r];
                float shE = dppf<0x130, 0xF, 0xF, false>(0.f, wE);  // shl1
                float shO = dppf<0x130, 0xF, 0xF, false>(0.f, wO);
                Ae = wE + wO;
                Ao = wO + shE + (skB ? shO : 0.f);
            }
        }
        if ((c & 3) == 3) {                  // renorm every 32 steps (R6 cadence)
            float vm = fmaxf(Ae, Ao);
            float m = wave_max(vm);
            int eb_ = (f2i(m) >> 23) & 0xFF;
            float sc = i2f((254 - eb_) << 23);
            Ae *= sc; Ao *= sc;
            S2 += eb_ - 127;
        }
        __syncthreads();                     // all waves done reading chunk c
        if (c + 1 < NCH) {                   // write chunk c+1 (held in p regs)
            float4* dst = (float4*)&sE[w * 768];
            dst[l] = p0; dst[64 + l] = p1; dst[128 + l] = p2;
        }
        p0 = q0; p1 = q1; p2 = q2;
        __syncthreads();                     // staged chunk visible
    }

    // per-(b,dir) result: Ae[64] | Ao[64] | S2   (132-float slot)
    float* out = ws + ((size_t)b * 2 + dir) * 132;
    out[l] = Ae;
    out[64 + l] = Ao;
    if (l == 0) ((int*)out)[128] = S2;
}

// Combine halves: f64 dot + bit-level exponent peel (verified rounds 4-6).
__global__ __launch_bounds__(256) void ctc_combine(
        const float* __restrict__ ws, float* __restrict__ loss) {
    const int b = blockIdx.x * 4 + (threadIdx.x >> 6);
    const int l = threadIdx.x & 63;
    const float* fb = ws + (size_t)(2 * b) * 132;
    const float* bw = ws + (size_t)(2 * b + 1) * 132;
    double pd = (double)fb[l] * bw[l] + (double)fb[64 + l] * bw[64 + l];
    #pragma unroll
    for (int m = 1; m < 64; m <<= 1) pd += __shfl_xor(pd, m);
    if (l == 0) {
        int s2 = ((const int*)fb)[128] + ((const int*)bw)[128];
        long long ud = __double_as_longlong(pd);
        int eb = (int)((ud >> 52) & 0x7FF);                 // biased exponent
        double md = __longlong_as_double(
            (ud & 0x000FFFFFFFFFFFFFLL) | 0x3FF0000000000000LL);  // [1,2)
        int s2tot = s2 + (eb - 1023);
        loss[b] = 2336.946274031532f
                - (float)s2tot * 0.6931471805599453f
                - __logf((float)md);
    }
}

__global__ __launch_bounds__(256) void ctc_mean_kernel(
        const float* __restrict__ loss, float* __restrict__ out) {
    const int tid = threadIdx.x;
    float v = loss[tid] + loss[tid + 256] + loss[tid + 512] + loss[tid + 768];
    #pragma unroll
    for (int m = 1; m < 64; m <<= 1) v += __shfl_xor(v, m);
    __shared__ float part[4];
    if ((tid & 63) == 0) part[tid >> 6] = v;
    __syncthreads();
    if (tid == 0) out[0] = (part[0] + part[1] + part[2] + part[3]) * (1.0f / (float)BB);
}

extern "C" void kernel_launch(void* const* d_in, const int* in_sizes, int n_in,
                              void* d_out, int out_size, void* d_ws, size_t ws_size,
                              hipStream_t stream) {
    const int* y_true = (const int*)d_in[0];     // [B, L] int32
    const float* y_pred = (const float*)d_in[1]; // [T, B, V] float32
    float* out = (float*)d_out;

    float* ws = (float*)d_ws;                    // 1024*2*132 floats ~ 1.06 MB
    float* lossbuf = ws + (size_t)BB * 2 * 132;  // [B] floats

    ctc_halves<<<256, 512, 0, stream>>>(y_true, y_pred, ws);
    ctc_combine<<<256, 256, 0, stream>>>(ws, lossbuf);
    ctc_mean_kernel<<<1, 256, 0, stream>>>(lossbuf, out);
}